// Round 1
// baseline (28265.396 us; speedup 1.0000x reference)
//
#include <hip/hip_runtime.h>
#include <hip/hip_bf16.h>
#include <stdint.h>

#define BSZ  128
#define TLEN 8192
#define MDIM 64
#define SDIM 512
#define NEG_BIG (-1e30f)

typedef _Float16 h2 __attribute__((ext_vector_type(2)));

__device__ __forceinline__ float dot2(h2 a, h2 b, float c) {
#if __has_builtin(__builtin_amdgcn_fdot2)
  return __builtin_amdgcn_fdot2(a, b, c, false);
#else
  return c + (float)a.x * (float)b.x + (float)a.y * (float)b.y;
#endif
}

// Extract symbol index from one-hot rows: sym[b,t] = argmax_m x[b,t,m]
__global__ void sym_kernel(const float* __restrict__ x, uint8_t* __restrict__ sym) {
  int i = blockIdx.x * blockDim.x + threadIdx.x;  // flat (b,t)
  const float4* p = (const float4*)(x + (size_t)i * MDIM);
  int idx = 0;
  #pragma unroll
  for (int j = 0; j < 16; ++j) {
    float4 v = p[j];
    if (v.x > 0.5f) idx = 4*j + 0;
    if (v.y > 0.5f) idx = 4*j + 1;
    if (v.z > 0.5f) idx = 4*j + 2;
    if (v.w > 0.5f) idx = 4*j + 3;
  }
  sym[i] = (uint8_t)idx;
}

// One block per batch. 1024 threads: thread t owns A[h*256 .. h*256+255, col]
// (col = t&511, h = t>>9) as 128 f16x2 registers. Whole T-loop in-kernel.
__global__ __launch_bounds__(1024) void hmm_fwd(
    const float* __restrict__ A, const float* __restrict__ Bm,
    const uint8_t* __restrict__ sym, float* __restrict__ out) {
  const int b   = blockIdx.x;
  const int t   = threadIdx.x;
  const int col = t & (SDIM - 1);
  const int h   = t >> 9;
  const int wv  = t >> 6;

  __shared__ __align__(16) _Float16 p_lds[SDIM];
  __shared__ float partial[SDIM];
  __shared__ float red[8];

  // ---- load A half-column into registers as f16 pairs (one-time) ----
  h2 Areg[128];
  #pragma unroll
  for (int j = 0; j < 128; ++j) {
    float a0 = A[(size_t)(h * 256 + 2 * j)     * SDIM + col];
    float a1 = A[(size_t)(h * 256 + 2 * j + 1) * SDIM + col];
    h2 v; v.x = (_Float16)a0; v.y = (_Float16)a1;
    Areg[j] = v;
  }

  const uint8_t* symb = sym + (size_t)b * TLEN;

  // ---- init: alpha0 = log(B[sym0,:] + eps) + [0, -inf, -inf, ...] ----
  float alphaReg = 0.f;
  if (t < SDIM) {
    int s0 = symb[0];
    alphaReg = __logf(Bm[s0 * SDIM + col] + 1e-16f) + (col == 0 ? 0.f : NEG_BIG);
  }
  // logE pipeline: logE_cur is for the step about to be processed
  int   symNext  = symb[1];
  float logE_cur = __logf(Bm[symNext * SDIM + col] + 1e-16f);
  symNext = symb[2];

  for (int step = 1; step < TLEN; ++step) {
    // ---- max over states (threads t<512 hold alpha) ----
    float mx = alphaReg;
    #pragma unroll
    for (int off = 32; off; off >>= 1) mx = fmaxf(mx, __shfl_xor(mx, off));
    if (t < SDIM && (t & 63) == 0) red[wv] = mx;
    __syncthreads();                       // red ready; prev-step p reads done
    float m = red[0];
    #pragma unroll
    for (int k = 1; k < 8; ++k) m = fmaxf(m, red[k]);

    if (t < SDIM) p_lds[col] = (_Float16)__expf(alphaReg - m);
    __syncthreads();                       // p ready

    // ---- prefetch next step's emission row (hidden under dot phase) ----
    float eNxt  = Bm[symNext * SDIM + col];
    int   symNN = symb[(step + 2 <= TLEN - 1) ? step + 2 : TLEN - 1];

    // ---- dot: r_partial[col] = sum_{s in half h} p[s] * A[s,col] ----
    const uint32_t* p32 = (const uint32_t*)p_lds + h * 128;
    float a0 = 0.f, a1 = 0.f, a2 = 0.f, a3 = 0.f;
    #pragma unroll
    for (int j = 0; j < 128; j += 4) {
      uint4 pv = *(const uint4*)(p32 + j);
      a0 = dot2(Areg[j + 0], __builtin_bit_cast(h2, pv.x), a0);
      a1 = dot2(Areg[j + 1], __builtin_bit_cast(h2, pv.y), a1);
      a2 = dot2(Areg[j + 2], __builtin_bit_cast(h2, pv.z), a2);
      a3 = dot2(Areg[j + 3], __builtin_bit_cast(h2, pv.w), a3);
    }
    float acc = (a0 + a1) + (a2 + a3);

    if (h == 1) partial[col] = acc;
    __syncthreads();                       // partials ready
    if (h == 0) {
      float r = acc + partial[col];
      alphaReg = __logf(r + 1e-16f) + m + logE_cur;
    }
    logE_cur = __logf(eNxt + 1e-16f);
    symNext  = symNN;
  }

  // ---- outputs: alpha_T then loglik ----
  if (t < SDIM) out[(size_t)b * SDIM + col] = alphaReg;

  float mx = alphaReg;
  #pragma unroll
  for (int off = 32; off; off >>= 1) mx = fmaxf(mx, __shfl_xor(mx, off));
  if (t < SDIM && (t & 63) == 0) red[wv] = mx;
  __syncthreads();
  float mf = red[0];
  #pragma unroll
  for (int k = 1; k < 8; ++k) mf = fmaxf(mf, red[k]);

  float se = (t < SDIM) ? __expf(alphaReg - mf) : 0.f;
  #pragma unroll
  for (int off = 32; off; off >>= 1) se += __shfl_xor(se, off);
  __syncthreads();                         // done reading red before rewrite
  if (t < SDIM && (t & 63) == 0) red[wv] = se;
  __syncthreads();
  if (t == 0) {
    float tot = 0.f;
    #pragma unroll
    for (int k = 0; k < 8; ++k) tot += red[k];
    out[(size_t)BSZ * SDIM + b] = __logf(tot + SDIM * 1e-16f) + mf;
  }
}

extern "C" void kernel_launch(void* const* d_in, const int* in_sizes, int n_in,
                              void* d_out, int out_size, void* d_ws, size_t ws_size,
                              hipStream_t stream) {
  const float* x  = (const float*)d_in[0];
  const float* A  = (const float*)d_in[1];
  const float* Bm = (const float*)d_in[2];
  float* out = (float*)d_out;
  uint8_t* sym = (uint8_t*)d_ws;           // BSZ*TLEN = 1MB scratch

  sym_kernel<<<(BSZ * TLEN) / 256, 256, 0, stream>>>(x, sym);
  hmm_fwd<<<BSZ, 1024, 0, stream>>>(A, Bm, sym, out);
}

// Round 2
// 10084.528 us; speedup vs baseline: 2.8028x; 2.8028x over previous
//
#include <hip/hip_runtime.h>
#include <stdint.h>

#define BSZ  128
#define TLEN 8192
#define MDIM 64
#define SDIM 512
#define NEG_BIG (-1e30f)

// ---- 8-bit dot product: 4 MACs per instruction, exact i32 accumulation ----
#if __has_builtin(__builtin_amdgcn_udot4)
  #define QA 255
  __device__ __forceinline__ int dot4(unsigned a, unsigned b, int c) {
    return (int)__builtin_amdgcn_udot4(a, b, (unsigned)c, false);
  }
#elif __has_builtin(__builtin_amdgcn_sdot4)
  #define QA 127   // keep bytes in [0,127] so signed == unsigned
  __device__ __forceinline__ int dot4(unsigned a, unsigned b, int c) {
    return __builtin_amdgcn_sdot4((int)a, (int)b, c, false);
  }
#else
  #define QA 255
  __device__ __forceinline__ int dot4(unsigned a, unsigned b, int c) {
    c += (int)((a & 0xffu) * (b & 0xffu));
    c += (int)(((a >> 8) & 0xffu) * ((b >> 8) & 0xffu));
    c += (int)(((a >> 16) & 0xffu) * ((b >> 16) & 0xffu));
    c += (int)((a >> 24) * (b >> 24));
    return c;
  }
#endif

// Extract symbol index from one-hot rows: sym[b,t] = argmax_m x[b,t,m]
__global__ void sym_kernel(const float* __restrict__ x, uint8_t* __restrict__ sym) {
  int i = blockIdx.x * blockDim.x + threadIdx.x;  // flat (b,t)
  const float4* p = (const float4*)(x + (size_t)i * MDIM);
  int idx = 0;
  #pragma unroll
  for (int j = 0; j < 16; ++j) {
    float4 v = p[j];
    if (v.x > 0.5f) idx = 4*j + 0;
    if (v.y > 0.5f) idx = 4*j + 1;
    if (v.z > 0.5f) idx = 4*j + 2;
    if (v.w > 0.5f) idx = 4*j + 3;
  }
  sym[i] = (uint8_t)idx;
}

// Per-column max of A (for quantization scale). One 64-thread block per column.
__global__ void colmax_kernel(const float* __restrict__ A, float* __restrict__ cmax) {
  int c = blockIdx.x, l = threadIdx.x;
  float m = 0.f;
  for (int r = l; r < SDIM; r += 64) m = fmaxf(m, A[(size_t)r * SDIM + c]);
  #pragma unroll
  for (int off = 32; off; off >>= 1) m = fmaxf(m, __shfl_xor(m, off));
  if (l == 0) cmax[c] = m;
}

// Pack A column-major as u8 row-quads: Aq[c*128 + j] bytes = round(QA*A[4j+b][c]/cmax[c])
__global__ void pack_kernel(const float* __restrict__ A, const float* __restrict__ cmax,
                            unsigned* __restrict__ Aq) {
  int id = blockIdx.x * 256 + threadIdx.x;   // 512*128 = 65536 ids
  int c = id >> 7, j = id & 127;
  float s = (float)QA / cmax[c];
  unsigned q = 0;
  #pragma unroll
  for (int bb = 0; bb < 4; ++bb) {
    float v = A[(size_t)(4 * j + bb) * SDIM + c];
    int qi = (int)(v * s + 0.5f);
    if (qi > QA) qi = QA;
    q |= (unsigned)qi << (8 * bb);
  }
  Aq[c * 128 + j] = q;
}

// One block per batch; 1024 threads.
//  col-owner role (t<512): state c=t; holds alpha, max-reduce, p-quant, combine+log.
//  dot role (all): row-group g=t>>7 (rows 64g..64g+63), cols k0..k0+3, A in 64 VGPRs (u8).
__global__ __launch_bounds__(1024) void hmm_fwd(
    const unsigned* __restrict__ Aq, const float* __restrict__ cmax,
    const float* __restrict__ Bm, const uint8_t* __restrict__ sym,
    float* __restrict__ out) {
  const int b  = blockIdx.x;
  const int t  = threadIdx.x;
  const int c  = t & (SDIM - 1);
  const int wv = t >> 6;
  const int g  = t >> 7;              // row group 0..7
  const int k0 = (t & 127) * 4;       // 4 output cols per dot-thread

  __shared__ unsigned p8[SDIM / 4];   // p quantized u8, 512 bytes
  __shared__ int part[8][SDIM];       // per-group partial dots, 16KB
  __shared__ float red[8];

  // ---- load this thread's A block into registers: 4 cols x 16 row-quads ----
  unsigned Areg[4][16];
  #pragma unroll
  for (int k = 0; k < 4; ++k) {
    const uint4* src = (const uint4*)(Aq + (size_t)(k0 + k) * 128 + g * 16);
    #pragma unroll
    for (int jj = 0; jj < 4; ++jj) {
      uint4 v = src[jj];
      Areg[k][4*jj+0] = v.x; Areg[k][4*jj+1] = v.y;
      Areg[k][4*jj+2] = v.z; Areg[k][4*jj+3] = v.w;
    }
  }

  const uint8_t* symb = sym + (size_t)b * TLEN;
  const float cscale = (t < SDIM) ? (cmax[c] * (1.0f / ((float)QA * (float)QA))) : 0.f;

  // ---- init: alpha0 = log(B[sym0,:]+eps) + [0,-inf,...] ----
  float alphaReg = NEG_BIG;
  int   symNext = 0;
  float logE_cur = 0.f;
  if (t < SDIM) {
    int s0 = symb[0];
    alphaReg = __logf(Bm[s0 * SDIM + c] + 1e-16f) + (c == 0 ? 0.f : NEG_BIG);
    symNext  = symb[1];
    logE_cur = __logf(Bm[symNext * SDIM + c] + 1e-16f);
    symNext  = symb[2];
  }

  for (int step = 1; step < TLEN; ++step) {
    // ---- phase 1: m = max over states ----
    if (t < SDIM) {
      float mx = alphaReg;
      #pragma unroll
      for (int off = 32; off; off >>= 1) mx = fmaxf(mx, __shfl_xor(mx, off));
      if ((t & 63) == 0) red[wv] = mx;
    }
    __syncthreads();                    // (A) red ready; prev combine-reads done
    float m = red[0];
    #pragma unroll
    for (int k = 1; k < 8; ++k) m = fmaxf(m, red[k]);

    // ---- phase 2: p = exp(alpha-m), quantize to u8 ----
    if (t < SDIM) {
      float p = __expf(alphaReg - m);
      unsigned q = (unsigned)(p * (float)QA + 0.5f);
      ((uint8_t*)p8)[c] = (uint8_t)q;
    }
    __syncthreads();                    // (B) p8 ready

    // prefetch next step's emission row (hides under dot phase)
    float eNxt = 0.f; int symNN = 0;
    if (t < SDIM) {
      eNxt  = Bm[symNext * SDIM + c];
      symNN = symb[(step + 2 <= TLEN - 1) ? step + 2 : TLEN - 1];
    }

    // ---- phase 3: dot. rows 64g..64g+63, cols k0..k0+3 ----
    const uint4* pv = (const uint4*)p8 + 4 * g;   // wave-uniform -> LDS broadcast
    uint4 P0 = pv[0], P1 = pv[1], P2 = pv[2], P3 = pv[3];
    unsigned pw[16] = {P0.x,P0.y,P0.z,P0.w, P1.x,P1.y,P1.z,P1.w,
                       P2.x,P2.y,P2.z,P2.w, P3.x,P3.y,P3.z,P3.w};
    int a0 = 0, a1 = 0, a2 = 0, a3 = 0;
    #pragma unroll
    for (int j = 0; j < 16; ++j) {
      a0 = dot4(pw[j], Areg[0][j], a0);
      a1 = dot4(pw[j], Areg[1][j], a1);
      a2 = dot4(pw[j], Areg[2][j], a2);
      a3 = dot4(pw[j], Areg[3][j], a3);
    }
    *(int4*)&part[g][k0] = make_int4(a0, a1, a2, a3);
    __syncthreads();                    // (C) partials ready

    // ---- phase 4: combine + log (col-owner) ----
    if (t < SDIM) {
      int s = part[0][c] + part[1][c] + part[2][c] + part[3][c]
            + part[4][c] + part[5][c] + part[6][c] + part[7][c];
      float r = (float)s * cscale;
      alphaReg = __logf(r + 1e-16f) + m + logE_cur;
      logE_cur = __logf(eNxt + 1e-16f);
      symNext  = symNN;
    }
  }

  // ---- outputs: alpha_T then loglik ----
  if (t < SDIM) out[(size_t)b * SDIM + c] = alphaReg;

  if (t < SDIM) {
    float mx = alphaReg;
    #pragma unroll
    for (int off = 32; off; off >>= 1) mx = fmaxf(mx, __shfl_xor(mx, off));
    if ((t & 63) == 0) red[wv] = mx;
  }
  __syncthreads();
  float mf = red[0];
  #pragma unroll
  for (int k = 1; k < 8; ++k) mf = fmaxf(mf, red[k]);

  float se = 0.f;
  if (t < SDIM) {
    se = __expf(alphaReg - mf);
    #pragma unroll
    for (int off = 32; off; off >>= 1) se += __shfl_xor(se, off);
  }
  __syncthreads();                      // red reads done before rewrite
  if (t < SDIM && (t & 63) == 0) red[wv] = se;
  __syncthreads();
  if (t == 0) {
    float tot = 0.f;
    #pragma unroll
    for (int k = 0; k < 8; ++k) tot += red[k];
    out[(size_t)BSZ * SDIM + b] = __logf(tot + SDIM * 1e-16f) + mf;
  }
}

extern "C" void kernel_launch(void* const* d_in, const int* in_sizes, int n_in,
                              void* d_out, int out_size, void* d_ws, size_t ws_size,
                              hipStream_t stream) {
  const float* x  = (const float*)d_in[0];
  const float* A  = (const float*)d_in[1];
  const float* Bm = (const float*)d_in[2];
  float* out = (float*)d_out;

  uint8_t*  sym  = (uint8_t*)d_ws;                                  // 1 MB
  unsigned* Aq   = (unsigned*)((char*)d_ws + (1 << 20));            // 256 KB
  float*    cmax = (float*)((char*)d_ws + (1 << 20) + (256 << 10)); // 2 KB

  sym_kernel<<<(BSZ * TLEN) / 256, 256, 0, stream>>>(x, sym);
  colmax_kernel<<<SDIM, 64, 0, stream>>>(A, cmax);
  pack_kernel<<<(SDIM * 128) / 256, 256, 0, stream>>>(A, cmax, Aq);
  hmm_fwd<<<BSZ, 1024, 0, stream>>>(Aq, cmax, Bm, sym, out);
}